// Round 5
// baseline (526.784 us; speedup 1.0000x reference)
//
#include <hip/hip_runtime.h>
#include <math.h>

// Problem constants (fixed by reference): B=1024, NMAX=128, D=256, NUM=4
#define BB   1024
#define DD   256
#define LOGD 5.5451774444795624753f   // log(256)

typedef __attribute__((ext_vector_type(8))) short short8;   // 8 bf16 = 4 VGPRs
typedef __attribute__((ext_vector_type(4))) float f32x4;    // MFMA acc

__device__ __forceinline__ float wave_sum(float v){
  #pragma unroll
  for (int off=32; off>0; off>>=1) v += __shfl_xor(v, off, 64);
  return v;
}
__device__ __forceinline__ float wave_max(float v){
  #pragma unroll
  for (int off=32; off>0; off>>=1) v = fmaxf(v, __shfl_xor(v, off, 64));
  return v;
}
__device__ __forceinline__ float fast_tanh(float x){
  return 1.0f - 2.0f/(__expf(2.0f*x)+1.0f);
}
__device__ __forceinline__ unsigned short f2bf(float f){
  unsigned int u = __float_as_uint(f);
  unsigned int r = u + 0x7FFFu + ((u >> 16) & 1u);   // RNE
  return (unsigned short)(r >> 16);
}
// s16 fixed-point codec for log-domain LDS state (range +-64, quantum 2^-9)
__device__ __forceinline__ short enc16(float a){
  float c = fminf(fmaxf(a*512.f, -32767.f), 32767.f);
  return (short)__float2int_rn(c);
}
__device__ __forceinline__ float dec16(short v){ return (float)v * (1.f/512.f); }

// ---- K1: segment bounds via binary search (batch is sorted) ----
__global__ void k_bounds(const int* __restrict__ batch, int T, int* __restrict__ starts){
  int b = blockIdx.x*blockDim.x + threadIdx.x;
  if (b > BB) return;
  int lo = 0, hi = T;
  while (lo < hi){ int mid = (lo+hi)>>1; if (batch[mid] < b) lo = mid+1; else hi = mid; }
  starts[b] = lo;
}

// ---- K1b: scalar parameter chain ----
// P: [0..3]=r [4..7]=1/(b1+r) [8..11]=1/(b2+r) [12..15]=log_mu@k [16..19]=b3 [20..23]=1/(b3+r)
__global__ void k_params(const float* __restrict__ rho, const float* __restrict__ a1,
                         const float* __restrict__ a2, const float* __restrict__ a3,
                         float* __restrict__ P){
  if (threadIdx.x != 0 || blockIdx.x != 0) return;
  float lm = -LOGD, z1 = 0.f;
  for (int k=0;k<4;k++){
    float r  = log1pf(expf(rho[k]));
    float b1 = log1pf(expf(a1[k]));
    float b2 = log1pf(expf(a2[k]));
    float b3 = log1pf(expf(a3[k]));
    P[k]    = r;
    P[4+k]  = 1.f/(b1+r);
    P[8+k]  = 1.f/(b2+r);
    P[12+k] = lm;              // mu used by S-update of iteration k
    P[16+k] = b3;
    P[20+k] = 1.f/(b3+r);
    float lmn = (b3*(-LOGD) - z1 + r*lm)/(b3+r);
    z1 += r*(expf(lmn)-expf(lm));
    lm = lmn;
  }
}

// ---- K1c: one-time W1 fp32 -> bf16 cast (512x256) ----
__global__ void k_castw(const float* __restrict__ W1, unsigned short* __restrict__ w1b){
  const int t = blockIdx.x*256 + threadIdx.x;   // 16384 threads
  #pragma unroll
  for (int i=0;i<2;i++){
    const int idx = (t*2 + i)*4;                // float4 index
    const float4 v = *(const float4*)(W1 + idx);
    *(ushort4*)(w1b + idx) = make_ushort4(f2bf(v.x), f2bf(v.y), f2bf(v.z), f2bf(v.w));
  }
}

// ---- K2: fused MLP via bf16 MFMA ----
// Tile M=64 x N=256 (hidden half), 256 thr (4 waves), wave tile 64x64 (4x4 acc).
// X staged once in LDS (full K=256, fp32->bf16, ONE barrier); B-fragments read
// DIRECTLY from global w1b (256 KB, L2-resident) - no W LDS round-trip, no
// k-loop barriers. LDS row stride 264 shorts -> conflict-free b128 frag reads.
#define LPX 264
__global__ __launch_bounds__(256, 4) void k_mlp(
    const float* __restrict__ x, const unsigned short* __restrict__ w1b,
    const float* __restrict__ W2, float* __restrict__ logits, int T)
{
  __shared__ unsigned short Xs[64*LPX];    // 33792 B
  __shared__ float lred[64];
  const int hh = blockIdx.x;   // hidden half 0..1
  const int bx = blockIdx.y;   // row tile
  const int tid = threadIdx.x;
  if (tid < 64) lred[tid] = 0.f;

  // stage X tile (64 rows x 256 k): thread t -> row t>>2, 64-col segment t&3
  {
    const int srow = tid >> 2, sseg = tid & 3;
    const int grow = bx*64 + srow;
    #pragma unroll
    for (int i=0;i<16;i++){
      float4 v = make_float4(0.f,0.f,0.f,0.f);
      if (grow < T) v = *(const float4*)(x + (size_t)grow*DD + sseg*64 + i*4);
      *(ushort4*)&Xs[srow*LPX + sseg*64 + i*4] =
          make_ushort4(f2bf(v.x), f2bf(v.y), f2bf(v.z), f2bf(v.w));
    }
  }
  __syncthreads();

  const int l = tid & 63;
  const int wn = tid >> 6;            // wave 0..3 = N quarter (64 hidden each)
  const int lr = l & 15, quad = l >> 4;

  f32x4 acc[4][4];
  #pragma unroll
  for (int mi=0;mi<4;mi++)
    #pragma unroll
    for (int ni=0;ni<4;ni++) acc[mi][ni] = (f32x4){0.f,0.f,0.f,0.f};

  #pragma unroll
  for (int ks=0; ks<8; ks++){
    short8 afr[4], bfr[4];
    #pragma unroll
    for (int ni=0;ni<4;ni++)
      bfr[ni] = *(const short8*)(w1b + (size_t)(hh*256 + wn*64 + ni*16 + lr)*DD + ks*32 + quad*8);
    #pragma unroll
    for (int mi=0;mi<4;mi++)
      afr[mi] = *(const short8*)&Xs[(mi*16 + lr)*LPX + ks*32 + quad*8];
    #pragma unroll
    for (int mi=0;mi<4;mi++)
      #pragma unroll
      for (int ni=0;ni<4;ni++)
        acc[mi][ni] = __builtin_amdgcn_mfma_f32_16x16x32_bf16(afr[mi], bfr[ni], acc[mi][ni], 0, 0, 0);
  }

  // epilogue: tanh + dot W2 + reduce over the 16-lane hidden group
  float w2v[4];
  #pragma unroll
  for (int ni=0;ni<4;ni++) w2v[ni] = W2[hh*256 + wn*64 + ni*16 + lr];
  #pragma unroll
  for (int mi=0;mi<4;mi++){
    float p[4];
    #pragma unroll
    for (int v=0; v<4; v++){
      p[v] = fast_tanh(acc[mi][0][v])*w2v[0] + fast_tanh(acc[mi][1][v])*w2v[1]
           + fast_tanh(acc[mi][2][v])*w2v[2] + fast_tanh(acc[mi][3][v])*w2v[3];
      #pragma unroll
      for (int off=1; off<16; off<<=1) p[v] += __shfl_xor(p[v], off, 64);
    }
    if (lr == 0){
      #pragma unroll
      for (int v=0; v<4; v++)
        atomicAdd(&lred[mi*16 + quad*4 + v], p[v]);
    }
  }
  __syncthreads();
  if (tid < 64){
    const int grow = bx*64 + tid;
    if (grow < T) atomicAdd(logits + grow, lred[tid]);
  }
}

// ---- K3: per-segment softmax -> lq0 = log(q0+1e-8), plus per-row eta
// trajectory E[t] = {eta_0..eta_3} (eta entering iteration k) - the eta/z2
// recurrence depends only on lq0[t] and P, so it's hoisted out of the solver.
__global__ void k_seg_softmax(const float* __restrict__ logits, const int* __restrict__ starts,
                              const float* __restrict__ P,
                              float* __restrict__ lq0, float4* __restrict__ E)
{
  const int b = blockIdx.x;
  const int start = starts[b], len = starts[b+1]-start;
  const int l = threadIdx.x; // 64 threads = 1 wave
  float v0 = (l      < len) ? logits[start+l]    : -3.0e38f;
  float v1 = (l+64   < len) ? logits[start+l+64] : -3.0e38f;
  float m = wave_max(fmaxf(v0,v1));
  float e0 = (l    < len) ? __expf(v0-m) : 0.f;
  float e1 = (l+64 < len) ? __expf(v1-m) : 0.f;
  float s = wave_sum(e0+e1);
  float inv = 1.f/(s + 1e-16f);
  float r0=P[0], r1=P[1], r2=P[2];
  float b30=P[16], b31=P[17], b32=P[18];
  float i0=P[20], i1=P[21], i2=P[22];
  #pragma unroll
  for (int h=0; h<2; h++){
    const int row = l + h*64;
    if (row < len){
      const float e = (h==0)? e0 : e1;
      const float lq = __logf(e*inv + 1e-8f);
      lq0[start+row] = lq;
      float4 ev;
      float eta = lq, z2 = 0.f, en;
      ev.x = eta;
      en = (b30*lq - z2 + r0*eta)*i0; z2 += r0*(__expf(en)-__expf(eta)); eta = en; ev.y = eta;
      en = (b31*lq - z2 + r1*eta)*i1; z2 += r1*(__expf(en)-__expf(eta)); eta = en; ev.z = eta;
      en = (b32*lq - z2 + r2*eta)*i2; z2 += r2*(__expf(en)-__expf(eta)); eta = en; ev.w = eta;
      E[start+row] = ev;
    }
  }
}

// ---- K4: BADMM solver, one block per batch ----
// A (log_s/log_t) as s16 in LDS (64 KB). No max-subtraction needed (exp args
// bounded above ~+7; validated rounds 3-4). eta/z2 precomputed in E (per-row
// scalars) -> fewer VGPRs (target <=48: round-3/4 evidence puts the
// 2-blocks/CU cliff between 32 and 56) and 2 fewer exps/row/iter.
// NOTE: do NOT force a high waves/EU minimum - round 3 proved it spills z[].
__global__ __launch_bounds__(1024, 4) void k_solver(
    const float* __restrict__ x, const float* __restrict__ lq0,
    const int* __restrict__ starts, const float* __restrict__ P,
    const float* __restrict__ E, float* __restrict__ out)
{
  __shared__ short A16[128*DD];     // 64 KB
  __shared__ float cols[2][DD];     // 2 KB ping-pong
  const int b = blockIdx.x;
  const int start = starts[b];
  const int len = starts[b+1] - start;
  const int tid = threadIdx.x;
  const int w = tid >> 6, l = tid & 63;
  const int n0 = w*8;
  int nv = len - n0; nv = nv < 0 ? 0 : (nv > 8 ? 8 : nv);

  float z[8][4];
  #pragma unroll
  for (int r=0;r<8;r++)
    #pragma unroll
    for (int j=0;j<4;j++) z[r][j]=0.f;
  #pragma unroll
  for (int r=0;r<8;r++){
    if (r < nv){
      const short q = enc16(lq0[start + n0 + r] - LOGD);
      const int base = (n0+r)*DD + l;
      #pragma unroll
      for (int j=0;j<4;j++) A16[base + 64*j] = q;
    }
  }
  if (tid < DD){ cols[0][tid] = 0.f; cols[1][tid] = 0.f; }

  for (int k=0;k<3;k++){
    const int p = k & 1;
    const float rk = P[k], ib1 = P[4+k], ib2 = P[8+k], muk = P[12+k];
    __syncthreads();   // (top) prev P3 stores + cols zero visible
    if (tid < DD) cols[p^1][tid] = 0.f;   // zero NEXT iter's buffer
    // ---- fused sweep: T-update (row LSE, no max) + column sum-exp ----
    float sp[4] = {0.f,0.f,0.f,0.f};
    #pragma unroll
    for (int r=0;r<8;r++){
      if (r < nv){
        const int n = n0 + r;
        const float etar = E[(size_t)(start+n)*4 + k];   // wave-uniform
        const float* xp = x + (size_t)(start+n)*DD + l;
        const int base = n*DD + l;
        float y[4];
        #pragma unroll
        for (int j=0;j<4;j++) y[j] = (xp[64*j] - z[r][j] + rk*dec16(A16[base+64*j])) * ib2;
        float se = 0.f;
        #pragma unroll
        for (int j=0;j<4;j++) se += __expf(y[j]);
        se = wave_sum(se);
        const float off = etar - __logf(se);   // lt = off + y
        #pragma unroll
        for (int j=0;j<4;j++){
          const float lt = off + y[j];
          A16[base+64*j] = enc16(lt);
          sp[j] += __expf((z[r][j] + rk*lt) * ib1);
        }
      }
    }
    if (nv > 0){
      #pragma unroll
      for (int j=0;j<4;j++) atomicAdd(&cols[p][l+64*j], sp[j]);
    }
    __syncthreads();   // (mid) cols[p] final
    float lsc[4];
    #pragma unroll
    for (int j=0;j<4;j++) lsc[j] = __logf(cols[p][l+64*j]);   // column LSE
    // ---- S-update + dual ascent, A: log_t -> log_s_new ----
    #pragma unroll
    for (int r=0;r<8;r++){
      if (r < nv){
        const int base = (n0+r)*DD + l;
        #pragma unroll
        for (int j=0;j<4;j++){
          const float lt  = dec16(A16[base+64*j]);
          const float lsn = muk + (z[r][j] + rk*lt) * ib1 - lsc[j];
          z[r][j] += rk*(__expf(lt) - __expf(lsn));
          A16[base+64*j] = enc16(lsn);
        }
      }
    }
  }
  // ---- k=3: T-update only + output (t = exp(eta3)/se * exp(y)) ----
  {
    const float rk = P[3], ib2 = P[8+3];
    __syncthreads();   // prev P3 stores visible; cols[1] was zeroed at k=2
    float op[4] = {0.f,0.f,0.f,0.f};
    #pragma unroll
    for (int r=0;r<8;r++){
      if (r < nv){
        const int n = n0 + r;
        const float eta3 = E[(size_t)(start+n)*4 + 3];
        const float* xp = x + (size_t)(start+n)*DD + l;
        const int base = n*DD + l;
        float y[4], xv[4];
        #pragma unroll
        for (int j=0;j<4;j++){
          xv[j] = xp[64*j];
          y[j] = (xv[j] - z[r][j] + rk*dec16(A16[base+64*j])) * ib2;
        }
        float ey[4], se = 0.f;
        #pragma unroll
        for (int j=0;j<4;j++){ ey[j] = __expf(y[j]); se += ey[j]; }
        se = wave_sum(se);
        const float rs = __expf(eta3) / se;
        #pragma unroll
        for (int j=0;j<4;j++) op[j] += xv[j]*ey[j]*rs;
      }
    }
    if (nv > 0){
      #pragma unroll
      for (int j=0;j<4;j++) atomicAdd(&cols[1][l+64*j], op[j]);
    }
    __syncthreads();
    if (tid < DD) out[(size_t)b*DD + tid] = 256.0f * cols[1][tid];
  }
}

extern "C" void kernel_launch(void* const* d_in, const int* in_sizes, int n_in,
                              void* d_out, int out_size, void* d_ws, size_t ws_size,
                              hipStream_t stream) {
  const float* x    = (const float*)d_in[0];
  const int*   batch= (const int*)d_in[1];
  const float* W1   = (const float*)d_in[2];
  const float* W2   = (const float*)d_in[3];
  const float* rho  = (const float*)d_in[4];
  const float* a1   = (const float*)d_in[5];
  const float* a2   = (const float*)d_in[6];
  const float* a3   = (const float*)d_in[7];
  float* out = (float*)d_out;
  const int T = in_sizes[1];   // total ragged rows

  // ws layout (E first for float4 alignment)
  float* E      = (float*)d_ws;              // 4T floats
  float* logits = E + (size_t)4*T;           // T floats
  float* lq0    = logits + T;                // T floats
  int*   starts = (int*)(lq0 + T);           // B+1 ints (padded)
  float* P      = (float*)(starts + 1028);   // 24 floats (padded to 32)
  unsigned short* w1b = (unsigned short*)(P + 32);  // 512*256 bf16

  k_bounds<<<dim3((BB+1+255)/256), 256, 0, stream>>>(batch, T, starts);
  k_params<<<1, 64, 0, stream>>>(rho, a1, a2, a3, P);
  k_castw<<<64, 256, 0, stream>>>(W1, w1b);
  hipMemsetAsync(logits, 0, (size_t)T*sizeof(float), stream);
  k_mlp<<<dim3(2, (T+63)/64), 256, 0, stream>>>(x, w1b, W2, logits, T);
  k_seg_softmax<<<BB, 64, 0, stream>>>(logits, starts, P, lq0, (float4*)E);
  k_solver<<<BB, 1024, 0, stream>>>(x, lq0, starts, P, E, out);
}

// Round 6
// 499.583 us; speedup vs baseline: 1.0544x; 1.0544x over previous
//
#include <hip/hip_runtime.h>
#include <math.h>

// Problem constants (fixed by reference): B=1024, NMAX=128, D=256, NUM=4
#define BB   1024
#define DD   256
#define LOGD 5.5451774444795624753f   // log(256)

typedef __attribute__((ext_vector_type(8))) short short8;   // 8 bf16 = 4 VGPRs
typedef __attribute__((ext_vector_type(4))) float f32x4;    // MFMA acc

__device__ __forceinline__ float wave_sum(float v){
  #pragma unroll
  for (int off=32; off>0; off>>=1) v += __shfl_xor(v, off, 64);
  return v;
}
__device__ __forceinline__ float wave_max(float v){
  #pragma unroll
  for (int off=32; off>0; off>>=1) v = fmaxf(v, __shfl_xor(v, off, 64));
  return v;
}
__device__ __forceinline__ float fast_tanh(float x){
  return 1.0f - 2.0f/(__expf(2.0f*x)+1.0f);
}
__device__ __forceinline__ unsigned short f2bf(float f){
  unsigned int u = __float_as_uint(f);
  unsigned int r = u + 0x7FFFu + ((u >> 16) & 1u);   // RNE
  return (unsigned short)(r >> 16);
}
// s16 fixed-point codec for log-domain LDS state (range +-64, quantum 2^-9)
__device__ __forceinline__ short enc16(float a){
  float c = fminf(fmaxf(a*512.f, -32767.f), 32767.f);
  return (short)__float2int_rn(c);
}
__device__ __forceinline__ float dec16(short v){ return (float)v * (1.f/512.f); }
// z dual-pack: 2 x s16 (quantum 2^-12, range +-8) per uint  -> halves z VGPRs
__device__ __forceinline__ unsigned zpack(float a, float b){
  int ia = __float2int_rn(fminf(fmaxf(a*4096.f, -32767.f), 32767.f));
  int ib = __float2int_rn(fminf(fmaxf(b*4096.f, -32767.f), 32767.f));
  return (unsigned)(ia & 0xffff) | ((unsigned)ib << 16);
}
#define ZLO(u) ((float)(short)(u) * (1.f/4096.f))
#define ZHI(u) ((float)(short)((u)>>16) * (1.f/4096.f))

// ---- K1: segment bounds via binary search (batch is sorted) ----
__global__ void k_bounds(const int* __restrict__ batch, int T, int* __restrict__ starts){
  int b = blockIdx.x*blockDim.x + threadIdx.x;
  if (b > BB) return;
  int lo = 0, hi = T;
  while (lo < hi){ int mid = (lo+hi)>>1; if (batch[mid] < b) lo = mid+1; else hi = mid; }
  starts[b] = lo;
}

// ---- K1b: scalar parameter chain ----
// P: [0..3]=r [4..7]=1/(b1+r) [8..11]=1/(b2+r) [12..15]=log_mu@k [16..19]=b3 [20..23]=1/(b3+r)
__global__ void k_params(const float* __restrict__ rho, const float* __restrict__ a1,
                         const float* __restrict__ a2, const float* __restrict__ a3,
                         float* __restrict__ P){
  if (threadIdx.x != 0 || blockIdx.x != 0) return;
  float lm = -LOGD, z1 = 0.f;
  for (int k=0;k<4;k++){
    float r  = log1pf(expf(rho[k]));
    float b1 = log1pf(expf(a1[k]));
    float b2 = log1pf(expf(a2[k]));
    float b3 = log1pf(expf(a3[k]));
    P[k]    = r;
    P[4+k]  = 1.f/(b1+r);
    P[8+k]  = 1.f/(b2+r);
    P[12+k] = lm;              // mu used by S-update of iteration k
    P[16+k] = b3;
    P[20+k] = 1.f/(b3+r);
    float lmn = (b3*(-LOGD) - z1 + r*lm)/(b3+r);
    z1 += r*(expf(lmn)-expf(lm));
    lm = lmn;
  }
}

// ---- K1c: one-time W1 fp32 -> bf16 cast (512x256) ----
__global__ void k_castw(const float* __restrict__ W1, unsigned short* __restrict__ w1b){
  const int t = blockIdx.x*256 + threadIdx.x;   // 16384 threads
  #pragma unroll
  for (int i=0;i<2;i++){
    const int idx = (t*2 + i)*4;                // float4 index
    const float4 v = *(const float4*)(W1 + idx);
    *(ushort4*)(w1b + idx) = make_ushort4(f2bf(v.x), f2bf(v.y), f2bf(v.z), f2bf(v.w));
  }
}

// ---- K2: fused MLP via bf16 MFMA ----
// 512 thr (8 waves), tile M=128 x N=128 (hidden quarter), BK=64.
// Both X (fp32->bf16 on the fly) and W (pre-cast bf16) staged in LDS with
// stride 72 shorts (conflict-free-enough b128 frags). LDS 37 KB -> 3-4 blk/CU.
// Round-5 lesson: direct-global B-fragments are 64-line scatters - latency-bound;
// LDS staging wins.
#define LPW 72
__global__ __launch_bounds__(512, 2) void k_mlp(
    const float* __restrict__ x, const unsigned short* __restrict__ w1b,
    const float* __restrict__ W2, float* __restrict__ logits, int T)
{
  __shared__ unsigned short Xs[128*LPW];   // 18432 B
  __shared__ unsigned short Ws[128*LPW];   // 18432 B
  __shared__ float lred[128];
  const int by = blockIdx.x;   // hidden quarter 0..3
  const int bx = blockIdx.y;   // row tile
  const int tid = threadIdx.x;
  if (tid < 128) lred[tid] = 0.f;

  const int l = tid & 63;
  const int w = tid >> 6;             // wave 0..7
  const int wm = w >> 2;              // M half (0..1)
  const int wn = w & 3;               // N quarter (0..3)
  const int lr = l & 15, quad = l >> 4;
  const int srow = tid >> 2;          // x-staging row 0..127
  const int sseg = tid & 3;           // 16-float segment of BK=64
  const int wrow = tid >> 3;          // w-staging row 0..63 (x2 halves)
  const int wseg = tid & 7;           // 8-short chunk

  f32x4 acc[4][2];
  #pragma unroll
  for (int mi=0;mi<4;mi++)
    #pragma unroll
    for (int ni=0;ni<2;ni++) acc[mi][ni] = (f32x4){0.f,0.f,0.f,0.f};

  for (int kt=0; kt<4; kt++){
    const int k0 = kt*64;
    // stage X tile (128 rows x 64 k, fp32 -> bf16): 4 float4 per thread
    {
      const int grow = bx*128 + srow;
      #pragma unroll
      for (int i=0;i<4;i++){
        float4 v = make_float4(0.f,0.f,0.f,0.f);
        if (grow < T) v = *(const float4*)(x + (size_t)grow*DD + k0 + sseg*16 + i*4);
        *(ushort4*)&Xs[srow*LPW + sseg*16 + i*4] =
            make_ushort4(f2bf(v.x), f2bf(v.y), f2bf(v.z), f2bf(v.w));
      }
    }
    // stage W tile (128 rows x 64 k, already bf16): 2 short8 per thread
    #pragma unroll
    for (int h=0; h<2; h++){
      const int r = h*64 + wrow;
      *(short8*)&Ws[r*LPW + wseg*8] =
          *(const short8*)(w1b + (size_t)(by*128 + r)*DD + k0 + wseg*8);
    }
    __syncthreads();
    #pragma unroll
    for (int ks=0; ks<2; ks++){
      short8 afr[4], bfr[2];
      #pragma unroll
      for (int mi=0;mi<4;mi++)
        afr[mi] = *(const short8*)&Xs[(wm*64 + mi*16 + lr)*LPW + ks*32 + quad*8];
      #pragma unroll
      for (int ni=0;ni<2;ni++)
        bfr[ni] = *(const short8*)&Ws[(wn*32 + ni*16 + lr)*LPW + ks*32 + quad*8];
      #pragma unroll
      for (int mi=0;mi<4;mi++)
        #pragma unroll
        for (int ni=0;ni<2;ni++)
          acc[mi][ni] = __builtin_amdgcn_mfma_f32_16x16x32_bf16(afr[mi], bfr[ni], acc[mi][ni], 0, 0, 0);
    }
    __syncthreads();
  }

  // epilogue: tanh + dot W2 + 16-lane reduce; C layout: col=lr, row=quad*4+v
  float w2v[2];
  #pragma unroll
  for (int ni=0;ni<2;ni++) w2v[ni] = W2[by*128 + wn*32 + ni*16 + lr];
  #pragma unroll
  for (int mi=0;mi<4;mi++){
    float p[4];
    #pragma unroll
    for (int v=0; v<4; v++){
      p[v] = fast_tanh(acc[mi][0][v])*w2v[0] + fast_tanh(acc[mi][1][v])*w2v[1];
      #pragma unroll
      for (int off=1; off<16; off<<=1) p[v] += __shfl_xor(p[v], off, 64);
    }
    if (lr == 0){
      #pragma unroll
      for (int v=0; v<4; v++)
        atomicAdd(&lred[wm*64 + mi*16 + quad*4 + v], p[v]);
    }
  }
  __syncthreads();
  if (tid < 128){
    const int grow = bx*128 + tid;
    if (grow < T) atomicAdd(logits + grow, lred[tid]);
  }
}

// ---- K3: per-segment softmax -> lq0 = log(q0+1e-8) + eta trajectory E ----
__global__ void k_seg_softmax(const float* __restrict__ logits, const int* __restrict__ starts,
                              const float* __restrict__ P,
                              float* __restrict__ lq0, float4* __restrict__ E)
{
  const int b = blockIdx.x;
  const int start = starts[b], len = starts[b+1]-start;
  const int l = threadIdx.x; // 64 threads = 1 wave
  float v0 = (l      < len) ? logits[start+l]    : -3.0e38f;
  float v1 = (l+64   < len) ? logits[start+l+64] : -3.0e38f;
  float m = wave_max(fmaxf(v0,v1));
  float e0 = (l    < len) ? __expf(v0-m) : 0.f;
  float e1 = (l+64 < len) ? __expf(v1-m) : 0.f;
  float s = wave_sum(e0+e1);
  float inv = 1.f/(s + 1e-16f);
  float r0=P[0], r1=P[1], r2=P[2];
  float b30=P[16], b31=P[17], b32=P[18];
  float i0=P[20], i1=P[21], i2=P[22];
  #pragma unroll
  for (int h=0; h<2; h++){
    const int row = l + h*64;
    if (row < len){
      const float e = (h==0)? e0 : e1;
      const float lq = __logf(e*inv + 1e-8f);
      lq0[start+row] = lq;
      float4 ev;
      float eta = lq, z2 = 0.f, en;
      ev.x = eta;
      en = (b30*lq - z2 + r0*eta)*i0; z2 += r0*(__expf(en)-__expf(eta)); eta = en; ev.y = eta;
      en = (b31*lq - z2 + r1*eta)*i1; z2 += r1*(__expf(en)-__expf(eta)); eta = en; ev.z = eta;
      en = (b32*lq - z2 + r2*eta)*i2; z2 += r2*(__expf(en)-__expf(eta)); eta = en; ev.w = eta;
      E[start+row] = ev;
    }
  }
}

// ---- K4: BADMM solver, one block per batch ----
// A state s16 in LDS (64 KB); z packed 2-per-uint in VGPRs (16 regs instead of
// 32) - round 3/4/5 bracketed the 8-waves/SIMD VGPR cliff between 32 (2 blk/CU)
// and 56 (1 blk/CU); target natural allocation <=48. No forced high min-waves
// (round 3: spills). No max-subtraction (exp args bounded above ~+7).
__global__ __launch_bounds__(1024, 4) void k_solver(
    const float* __restrict__ x,
    const int* __restrict__ starts, const float* __restrict__ P,
    const float* __restrict__ E, float* __restrict__ out)
{
  __shared__ short A16[128*DD];     // 64 KB
  __shared__ float cols[2][DD];     // 2 KB ping-pong
  const int b = blockIdx.x;
  const int start = starts[b];
  const int len = starts[b+1] - start;
  const int tid = threadIdx.x;
  const int w = tid >> 6, l = tid & 63;
  const int n0 = w*8;
  int nv = len - n0; nv = nv < 0 ? 0 : (nv > 8 ? 8 : nv);

  unsigned zp[8][2];
  #pragma unroll
  for (int r=0;r<8;r++){ zp[r][0]=0u; zp[r][1]=0u; }
  #pragma unroll
  for (int r=0;r<8;r++){
    if (r < nv){
      const short q = enc16(E[(size_t)(start + n0 + r)*4] - LOGD);  // eta0 = lq
      const int base = (n0+r)*DD + l;
      #pragma unroll
      for (int j=0;j<4;j++) A16[base + 64*j] = q;
    }
  }
  if (tid < DD){ cols[0][tid] = 0.f; cols[1][tid] = 0.f; }

  for (int k=0;k<3;k++){
    const int p = k & 1;
    const float rk = P[k], ib1 = P[4+k], ib2 = P[8+k], muk = P[12+k];
    __syncthreads();   // (top) prev P3 stores + cols zero visible
    if (tid < DD) cols[p^1][tid] = 0.f;   // zero NEXT iter's buffer
    // ---- fused sweep: T-update (row LSE, no max) + column sum-exp ----
    float sp[4] = {0.f,0.f,0.f,0.f};
    #pragma unroll
    for (int r=0;r<8;r++){
      if (r < nv){
        const int n = n0 + r;
        const float etar = E[(size_t)(start+n)*4 + k];   // row-uniform
        const float* xp = x + (size_t)(start+n)*DD + l;
        const int base = n*DD + l;
        float za[4] = { ZLO(zp[r][0]), ZHI(zp[r][0]), ZLO(zp[r][1]), ZHI(zp[r][1]) };
        float y[4];
        #pragma unroll
        for (int j=0;j<4;j++) y[j] = (xp[64*j] - za[j] + rk*dec16(A16[base+64*j])) * ib2;
        float se = 0.f;
        #pragma unroll
        for (int j=0;j<4;j++) se += __expf(y[j]);
        se = wave_sum(se);
        const float off = etar - __logf(se);   // lt = off + y
        #pragma unroll
        for (int j=0;j<4;j++){
          const float lt = off + y[j];
          A16[base+64*j] = enc16(lt);
          sp[j] += __expf((za[j] + rk*lt) * ib1);
        }
      }
    }
    if (nv > 0){
      #pragma unroll
      for (int j=0;j<4;j++) atomicAdd(&cols[p][l+64*j], sp[j]);
    }
    __syncthreads();   // (mid) cols[p] final
    float lsc[4];
    #pragma unroll
    for (int j=0;j<4;j++) lsc[j] = __logf(cols[p][l+64*j]);   // column LSE
    // ---- S-update + dual ascent, A: log_t -> log_s_new ----
    #pragma unroll
    for (int r=0;r<8;r++){
      if (r < nv){
        const int base = (n0+r)*DD + l;
        float za[4] = { ZLO(zp[r][0]), ZHI(zp[r][0]), ZLO(zp[r][1]), ZHI(zp[r][1]) };
        #pragma unroll
        for (int j=0;j<4;j++){
          const float lt  = dec16(A16[base+64*j]);
          const float lsn = muk + (za[j] + rk*lt) * ib1 - lsc[j];
          za[j] += rk*(__expf(lt) - __expf(lsn));
          A16[base+64*j] = enc16(lsn);
        }
        zp[r][0] = zpack(za[0], za[1]);
        zp[r][1] = zpack(za[2], za[3]);
      }
    }
  }
  // ---- k=3: T-update only + output (t = exp(eta3)/se * exp(y)) ----
  {
    const float rk = P[3], ib2 = P[8+3];
    __syncthreads();   // prev P3 stores visible; cols[1] was zeroed at k=2
    float op[4] = {0.f,0.f,0.f,0.f};
    #pragma unroll
    for (int r=0;r<8;r++){
      if (r < nv){
        const int n = n0 + r;
        const float eta3 = E[(size_t)(start+n)*4 + 3];
        const float* xp = x + (size_t)(start+n)*DD + l;
        const int base = n*DD + l;
        float za[4] = { ZLO(zp[r][0]), ZHI(zp[r][0]), ZLO(zp[r][1]), ZHI(zp[r][1]) };
        float y[4], xv[4];
        #pragma unroll
        for (int j=0;j<4;j++){
          xv[j] = xp[64*j];
          y[j] = (xv[j] - za[j] + rk*dec16(A16[base+64*j])) * ib2;
        }
        float ey[4], se = 0.f;
        #pragma unroll
        for (int j=0;j<4;j++){ ey[j] = __expf(y[j]); se += ey[j]; }
        se = wave_sum(se);
        const float rs = __expf(eta3) / se;
        #pragma unroll
        for (int j=0;j<4;j++) op[j] += xv[j]*ey[j]*rs;
      }
    }
    if (nv > 0){
      #pragma unroll
      for (int j=0;j<4;j++) atomicAdd(&cols[1][l+64*j], op[j]);
    }
    __syncthreads();
    if (tid < DD) out[(size_t)b*DD + tid] = 256.0f * cols[1][tid];
  }
}

extern "C" void kernel_launch(void* const* d_in, const int* in_sizes, int n_in,
                              void* d_out, int out_size, void* d_ws, size_t ws_size,
                              hipStream_t stream) {
  const float* x    = (const float*)d_in[0];
  const int*   batch= (const int*)d_in[1];
  const float* W1   = (const float*)d_in[2];
  const float* W2   = (const float*)d_in[3];
  const float* rho  = (const float*)d_in[4];
  const float* a1   = (const float*)d_in[5];
  const float* a2   = (const float*)d_in[6];
  const float* a3   = (const float*)d_in[7];
  float* out = (float*)d_out;
  const int T = in_sizes[1];   // total ragged rows

  // ws layout (E first for float4 alignment)
  float* E      = (float*)d_ws;              // 4T floats
  float* logits = E + (size_t)4*T;           // T floats
  float* lq0    = logits + T;                // T floats
  int*   starts = (int*)(lq0 + T);           // B+1 ints (padded)
  float* P      = (float*)(starts + 1028);   // 24 floats (padded to 32)
  unsigned short* w1b = (unsigned short*)(P + 32);  // 512*256 bf16

  k_bounds<<<dim3((BB+1+255)/256), 256, 0, stream>>>(batch, T, starts);
  k_params<<<1, 64, 0, stream>>>(rho, a1, a2, a3, P);
  k_castw<<<64, 256, 0, stream>>>(W1, w1b);
  hipMemsetAsync(logits, 0, (size_t)T*sizeof(float), stream);
  k_mlp<<<dim3(4, (T+127)/128), 512, 0, stream>>>(x, w1b, W2, logits, T);
  k_seg_softmax<<<BB, 64, 0, stream>>>(logits, starts, P, lq0, (float4*)E);
  k_solver<<<BB, 1024, 0, stream>>>(x, starts, P, E, out);
}

// Round 7
// 358.178 us; speedup vs baseline: 1.4707x; 1.3948x over previous
//
#include <hip/hip_runtime.h>
#include <math.h>

// Problem constants (fixed by reference): B=1024, NMAX=128, D=256, NUM=4
#define BB   1024
#define DD   256
#define LOGD 5.5451774444795624753f   // log(256)

typedef __attribute__((ext_vector_type(8))) short short8;   // 8 bf16 = 4 VGPRs
typedef __attribute__((ext_vector_type(4))) float f32x4;    // MFMA acc

__device__ __forceinline__ float wave_sum(float v){
  #pragma unroll
  for (int off=32; off>0; off>>=1) v += __shfl_xor(v, off, 64);
  return v;
}
__device__ __forceinline__ float wave_max(float v){
  #pragma unroll
  for (int off=32; off>0; off>>=1) v = fmaxf(v, __shfl_xor(v, off, 64));
  return v;
}
__device__ __forceinline__ float fast_tanh(float x){
  return 1.0f - 2.0f/(__expf(2.0f*x)+1.0f);
}
__device__ __forceinline__ unsigned short f2bf(float f){
  unsigned int u = __float_as_uint(f);
  unsigned int r = u + 0x7FFFu + ((u >> 16) & 1u);   // RNE
  return (unsigned short)(r >> 16);
}

// ---- K_pre: fused prologue (castW + bounds + params), one launch ----
// blocks 0..63: W1 fp32->bf16 cast; blocks 64..68: segment bounds; block 69: params.
__global__ void k_pre(const float* __restrict__ W1, unsigned short* __restrict__ w1b,
                      const int* __restrict__ batch, int T, int* __restrict__ starts,
                      const float* __restrict__ rho, const float* __restrict__ a1,
                      const float* __restrict__ a2, const float* __restrict__ a3,
                      float* __restrict__ P)
{
  const int blk = blockIdx.x, tid = threadIdx.x;
  if (blk < 64){
    const int t = blk*256 + tid;
    #pragma unroll
    for (int i=0;i<2;i++){
      const int idx = (t*2 + i)*4;
      const float4 v = *(const float4*)(W1 + idx);
      *(ushort4*)(w1b + idx) = make_ushort4(f2bf(v.x), f2bf(v.y), f2bf(v.z), f2bf(v.w));
    }
  } else if (blk < 69){
    const int b = (blk-64)*256 + tid;
    if (b <= BB){
      int lo = 0, hi = T;
      while (lo < hi){ int mid = (lo+hi)>>1; if (batch[mid] < b) lo = mid+1; else hi = mid; }
      starts[b] = lo;
    }
  } else if (tid == 0){
    // P: [0..3]=r [4..7]=1/(b1+r) [8..11]=1/(b2+r) [12..15]=log_mu@k [16..19]=b3 [20..23]=1/(b3+r)
    float lm = -LOGD, z1 = 0.f;
    for (int k=0;k<4;k++){
      float r  = log1pf(expf(rho[k]));
      float b1 = log1pf(expf(a1[k]));
      float b2 = log1pf(expf(a2[k]));
      float b3 = log1pf(expf(a3[k]));
      P[k]    = r;
      P[4+k]  = 1.f/(b1+r);
      P[8+k]  = 1.f/(b2+r);
      P[12+k] = lm;              // mu used by S-update of iteration k
      P[16+k] = b3;
      P[20+k] = 1.f/(b3+r);
      float lmn = (b3*(-LOGD) - z1 + r*lm)/(b3+r);
      z1 += r*(expf(lmn)-expf(lm));
      lm = lmn;
    }
  }
}

// ---- K2: fused MLP via bf16 MFMA (unchanged structure from round 6) ----
#define LPW 72
__global__ __launch_bounds__(512, 2) void k_mlp(
    const float* __restrict__ x, const unsigned short* __restrict__ w1b,
    const float* __restrict__ W2, float* __restrict__ logits, int T)
{
  __shared__ unsigned short Xs[128*LPW];   // 18432 B
  __shared__ unsigned short Ws[128*LPW];   // 18432 B
  __shared__ float lred[128];
  const int by = blockIdx.x;   // hidden quarter 0..3
  const int bx = blockIdx.y;   // row tile
  const int tid = threadIdx.x;
  if (tid < 128) lred[tid] = 0.f;

  const int l = tid & 63;
  const int w = tid >> 6;             // wave 0..7
  const int wm = w >> 2;              // M half (0..1)
  const int wn = w & 3;               // N quarter (0..3)
  const int lr = l & 15, quad = l >> 4;
  const int srow = tid >> 2;          // x-staging row 0..127
  const int sseg = tid & 3;           // 16-float segment of BK=64
  const int wrow = tid >> 3;          // w-staging row 0..63 (x2 halves)
  const int wseg = tid & 7;           // 8-short chunk

  f32x4 acc[4][2];
  #pragma unroll
  for (int mi=0;mi<4;mi++)
    #pragma unroll
    for (int ni=0;ni<2;ni++) acc[mi][ni] = (f32x4){0.f,0.f,0.f,0.f};

  for (int kt=0; kt<4; kt++){
    const int k0 = kt*64;
    {
      const int grow = bx*128 + srow;
      #pragma unroll
      for (int i=0;i<4;i++){
        float4 v = make_float4(0.f,0.f,0.f,0.f);
        if (grow < T) v = *(const float4*)(x + (size_t)grow*DD + k0 + sseg*16 + i*4);
        *(ushort4*)&Xs[srow*LPW + sseg*16 + i*4] =
            make_ushort4(f2bf(v.x), f2bf(v.y), f2bf(v.z), f2bf(v.w));
      }
    }
    #pragma unroll
    for (int h=0; h<2; h++){
      const int r = h*64 + wrow;
      *(short8*)&Ws[r*LPW + wseg*8] =
          *(const short8*)(w1b + (size_t)(by*128 + r)*DD + k0 + wseg*8);
    }
    __syncthreads();
    #pragma unroll
    for (int ks=0; ks<2; ks++){
      short8 afr[4], bfr[2];
      #pragma unroll
      for (int mi=0;mi<4;mi++)
        afr[mi] = *(const short8*)&Xs[(wm*64 + mi*16 + lr)*LPW + ks*32 + quad*8];
      #pragma unroll
      for (int ni=0;ni<2;ni++)
        bfr[ni] = *(const short8*)&Ws[(wn*32 + ni*16 + lr)*LPW + ks*32 + quad*8];
      #pragma unroll
      for (int mi=0;mi<4;mi++)
        #pragma unroll
        for (int ni=0;ni<2;ni++)
          acc[mi][ni] = __builtin_amdgcn_mfma_f32_16x16x32_bf16(afr[mi], bfr[ni], acc[mi][ni], 0, 0, 0);
    }
    __syncthreads();
  }

  float w2v[2];
  #pragma unroll
  for (int ni=0;ni<2;ni++) w2v[ni] = W2[by*128 + wn*32 + ni*16 + lr];
  #pragma unroll
  for (int mi=0;mi<4;mi++){
    float p[4];
    #pragma unroll
    for (int v=0; v<4; v++){
      p[v] = fast_tanh(acc[mi][0][v])*w2v[0] + fast_tanh(acc[mi][1][v])*w2v[1];
      #pragma unroll
      for (int off=1; off<16; off<<=1) p[v] += __shfl_xor(p[v], off, 64);
    }
    if (lr == 0){
      #pragma unroll
      for (int v=0; v<4; v++)
        atomicAdd(&lred[wm*64 + mi*16 + quad*4 + v], p[v]);
    }
  }
  __syncthreads();
  if (tid < 128){
    const int grow = bx*128 + tid;
    if (grow < T) atomicAdd(logits + grow, lred[tid]);
  }
}

// ---- K4: BADMM solver, one block per batch, SINGLE SWEEP PER ITERATION ----
// Sweep m fuses: S-update(k=m-1) + z dual-ascent + T-update(k=m) + column
// sum-exp for the next S-update. 4 A-sweeps total (theoretical minimum given
// the column-LSE dependency). A in fp32 (no s16 codec - r2 vs r4/r6 evidence:
// codec costs more than it saves at equal occupancy). Segment softmax fused
// into the prologue (each wave computes it redundantly). eta/z2 recurrence in
// registers (exact identity: sum_d t = exp(eta_old)). No max-subtraction (exp
// args bounded above ~+7, validated r4-r6). LDS 145 KB -> 1 block/CU (known).
// Do NOT force high min-waves/EU (r3: spills z[] to scratch, 243 MB).
__global__ __launch_bounds__(1024, 4) void k_solver(
    const float* __restrict__ x, const float* __restrict__ logits,
    const int* __restrict__ starts, const float* __restrict__ P,
    float* __restrict__ out)
{
  __shared__ float A[128*DD];      // 128 KB: log_s / log_t state
  __shared__ float red[16*DD];     // 16 KB: column partials
  __shared__ float colv[DD];       // 1 KB: column LSE
  const int b = blockIdx.x;
  const int start = starts[b];
  const int len = starts[b+1] - start;
  const int tid = threadIdx.x;
  const int w = tid >> 6, l = tid & 63;
  const int n0 = w*8;
  int nv = len - n0; nv = nv < 0 ? 0 : (nv > 8 ? 8 : nv);

  // scalar params (wave-uniform s_loads)
  const float r0=P[0], r1=P[1], r2=P[2], r3=P[3];
  const float i10=P[4], i11=P[5], i12=P[6];
  const float i20=P[8], i21=P[9], i22=P[10], i23=P[11];
  const float mu0=P[12], mu1=P[13], mu2=P[14];
  const float b30=P[16], b31=P[17], b32=P[18];
  const float e30=P[20], e31=P[21], e32=P[22];

  // ---- fused segment softmax (per-wave redundant) ----
  const float* lg = logits + start;
  float v0 = (l      < len) ? lg[l]    : -3.0e38f;
  float v1 = (l+64   < len) ? lg[l+64] : -3.0e38f;
  float sm = wave_max(fmaxf(v0,v1));
  float se0 = (l    < len) ? __expf(v0-sm) : 0.f;
  float se1 = (l+64 < len) ? __expf(v1-sm) : 0.f;
  float ssum = wave_sum(se0+se1);
  const float sinv = 1.f/(ssum + 1e-16f);
  const float esel = (n0 < 64) ? se0 : se1;   // wave-uniform selector

  float lq[8], eta[8], z2r[8];
  float z[8][4];
  #pragma unroll
  for (int r=0;r<8;r++){
    const float ev = __shfl(esel, (n0+r)&63, 64);
    lq[r]  = __logf(ev*sinv + 1e-8f);
    eta[r] = lq[r];
    z2r[r] = 0.f;
    #pragma unroll
    for (int j=0;j<4;j++) z[r][j]=0.f;
  }

  // ---- sweep 0: T-update(k=0) from registers + colsum for S(0) ----
  {
    float sp[4] = {0.f,0.f,0.f,0.f};
    #pragma unroll
    for (int r=0;r<8;r++){
      if (r < nv){
        const float* xp = x + (size_t)(start+n0+r)*DD + l;
        const int base = (n0+r)*DD + l;
        const float a0 = lq[r] - LOGD;        // initial log_s (uniform per row)
        float xv[4], y[4];
        #pragma unroll
        for (int j=0;j<4;j++) xv[j] = xp[64*j];
        #pragma unroll
        for (int j=0;j<4;j++) y[j] = (xv[j] + r0*a0) * i20;
        float se = 0.f;
        #pragma unroll
        for (int j=0;j<4;j++) se += __expf(y[j]);
        se = wave_sum(se);
        const float off = eta[r] - __logf(se);
        #pragma unroll
        for (int j=0;j<4;j++){
          const float lt = off + y[j];
          A[base+64*j] = lt;
          sp[j] += __expf((r0*lt) * i10);     // z=0
        }
        // eta advance k=0
        const float en = (b30*lq[r] - z2r[r] + r0*eta[r]) * e30;
        z2r[r] += r0*(__expf(en) - __expf(eta[r]));
        eta[r] = en;
      }
    }
    #pragma unroll
    for (int j=0;j<4;j++) red[w*DD + l + 64*j] = sp[j];
  }
  __syncthreads();
  if (tid < DD){
    float s = 0.f;
    #pragma unroll
    for (int ww=0; ww<16; ww++) s += red[ww*DD + tid];
    colv[tid] = __logf(s);
  }
  __syncthreads();

  // ---- sweeps 1..2: S(k-1) + z-update + T(k) + colsum(k) ----
  #pragma unroll
  for (int k=1;k<3;k++){
    const float rkm = (k==1)? r0 : r1;
    const float ib1m= (k==1)? i10 : i11;
    const float mum = (k==1)? mu0 : mu1;
    const float rk  = (k==1)? r1 : r2;
    const float ib1k= (k==1)? i11 : i12;
    const float ib2k= (k==1)? i21 : i22;
    const float b3k = (k==1)? b31 : b32;
    const float e3k = (k==1)? e31 : e32;
    float lsc[4];
    #pragma unroll
    for (int j=0;j<4;j++) lsc[j] = colv[l+64*j];
    float sp[4] = {0.f,0.f,0.f,0.f};
    #pragma unroll
    for (int r=0;r<8;r++){
      if (r < nv){
        const float* xp = x + (size_t)(start+n0+r)*DD + l;
        const int base = (n0+r)*DD + l;
        float xv[4];
        #pragma unroll
        for (int j=0;j<4;j++) xv[j] = xp[64*j];
        float y[4], lsn[4];
        #pragma unroll
        for (int j=0;j<4;j++){
          const float lt  = A[base+64*j];
          const float ys  = (z[r][j] + rkm*lt) * ib1m;
          lsn[j] = mum + ys - lsc[j];
          z[r][j] += rkm*(__expf(lt) - __expf(lsn[j]));
          y[j] = (xv[j] - z[r][j] + rk*lsn[j]) * ib2k;
        }
        float se = 0.f;
        #pragma unroll
        for (int j=0;j<4;j++) se += __expf(y[j]);
        se = wave_sum(se);
        const float off = eta[r] - __logf(se);
        #pragma unroll
        for (int j=0;j<4;j++){
          const float lt = off + y[j];
          A[base+64*j] = lt;
          sp[j] += __expf((z[r][j] + rk*lt) * ib1k);
        }
        const float en = (b3k*lq[r] - z2r[r] + rk*eta[r]) * e3k;
        z2r[r] += rk*(__expf(en) - __expf(eta[r]));
        eta[r] = en;
      }
    }
    #pragma unroll
    for (int j=0;j<4;j++) red[w*DD + l + 64*j] = sp[j];
    __syncthreads();
    if (tid < DD){
      float s = 0.f;
      #pragma unroll
      for (int ww=0; ww<16; ww++) s += red[ww*DD + tid];
      colv[tid] = __logf(s);
    }
    __syncthreads();
  }

  // ---- sweep 3: S(2) + z-update + T(3) + output ----
  {
    float lsc[4];
    #pragma unroll
    for (int j=0;j<4;j++) lsc[j] = colv[l+64*j];
    float op[4] = {0.f,0.f,0.f,0.f};
    #pragma unroll
    for (int r=0;r<8;r++){
      if (r < nv){
        const float* xp = x + (size_t)(start+n0+r)*DD + l;
        const int base = (n0+r)*DD + l;
        float xv[4];
        #pragma unroll
        for (int j=0;j<4;j++) xv[j] = xp[64*j];
        float y[4];
        #pragma unroll
        for (int j=0;j<4;j++){
          const float lt  = A[base+64*j];
          const float ys  = (z[r][j] + r2*lt) * i12;
          const float lsn = mu2 + ys - lsc[j];
          z[r][j] += r2*(__expf(lt) - __expf(lsn));
          y[j] = (xv[j] - z[r][j] + r3*lsn) * i23;
        }
        float ey[4], se = 0.f;
        #pragma unroll
        for (int j=0;j<4;j++){ ey[j] = __expf(y[j]); se += ey[j]; }
        se = wave_sum(se);
        const float rs = __expf(eta[r]) / se;   // t = ey * exp(eta3)/se
        #pragma unroll
        for (int j=0;j<4;j++) op[j] += xv[j]*ey[j]*rs;
      }
    }
    #pragma unroll
    for (int j=0;j<4;j++) red[w*DD + l + 64*j] = op[j];
    __syncthreads();
    if (tid < DD){
      float s = 0.f;
      #pragma unroll
      for (int ww=0; ww<16; ww++) s += red[ww*DD + tid];
      out[(size_t)b*DD + tid] = 256.0f * s;
    }
  }
}

extern "C" void kernel_launch(void* const* d_in, const int* in_sizes, int n_in,
                              void* d_out, int out_size, void* d_ws, size_t ws_size,
                              hipStream_t stream) {
  const float* x    = (const float*)d_in[0];
  const int*   batch= (const int*)d_in[1];
  const float* W1   = (const float*)d_in[2];
  const float* W2   = (const float*)d_in[3];
  const float* rho  = (const float*)d_in[4];
  const float* a1   = (const float*)d_in[5];
  const float* a2   = (const float*)d_in[6];
  const float* a3   = (const float*)d_in[7];
  float* out = (float*)d_out;
  const int T = in_sizes[1];   // total ragged rows

  float* logits = (float*)d_ws;              // T floats
  int*   starts = (int*)(logits + T);        // B+1 ints (padded to 1028)
  float* P      = (float*)(starts + 1028);   // 24 floats (padded to 32)
  unsigned short* w1b = (unsigned short*)(P + 32);  // 512*256 bf16

  k_pre<<<70, 256, 0, stream>>>(W1, w1b, batch, T, starts, rho, a1, a2, a3, P);
  hipMemsetAsync(logits, 0, (size_t)T*sizeof(float), stream);
  k_mlp<<<dim3(4, (T+127)/128), 512, 0, stream>>>(x, w1b, W2, logits, T);
  k_solver<<<BB, 1024, 0, stream>>>(x, logits, starts, P, out);
}